// Round 1
// baseline (296.049 us; speedup 1.0000x reference)
//
#include <hip/hip_runtime.h>

// ReActNet BasicBlock forward:
//   out = BN(binary_conv3x3(sign(x), scale*sign(w))) + x
// Implemented as XNOR-popcount conv over channel-bit-packed x with an
// explicit nonzero mask so sign(0)==0 is exact (padding too).

#define N_   64
#define C_   128
#define H_   56
#define W_   56
#define HW_  (H_*W_)       // 3136
#define PH_  (H_+2)        // 58
#define PW_  (W_+2)        // 58
#define PHW_ (PH_*PW_)     // 3364
#define NPIX (N_*HW_)      // 200704
#define NPAD (N_*PHW_)     // 215296

typedef unsigned long long u64;

// ---------------------------------------------------------------------------
// Kernel 1: weight prep. One wave per output channel.
//   scale[o] = mean|w[o,:,:,:]|
//   wbits[o][tap][j]: bit c = (w[o, 64j+c, tap] < 0)
//   A[o] = scale*gamma*rsqrt(var+eps), B[o] = beta - mean*gamma*rsqrt(var+eps)
// ---------------------------------------------------------------------------
__global__ void prep_w_kernel(const float* __restrict__ w,
                              const float* __restrict__ gamma,
                              const float* __restrict__ beta,
                              const float* __restrict__ bn_mean,
                              const float* __restrict__ bn_var,
                              u64* __restrict__ wbits,
                              float* __restrict__ A, float* __restrict__ B) {
    const int o = blockIdx.x;
    const int lane = threadIdx.x;          // 0..63
    const float* wo = w + o * 1152;        // [i][kh][kw] flat, i*9 + tap

    // mean |w| over 1152 elems
    float s = 0.f;
    #pragma unroll
    for (int k = 0; k < 18; k++) s += fabsf(wo[k * 64 + lane]);
    #pragma unroll
    for (int off = 32; off > 0; off >>= 1) s += __shfl_down(s, off);
    float scale = __shfl(s, 0) * (1.0f / 1152.0f);

    // pack sign bits via ballot: word j covers channels 64j..64j+63
    #pragma unroll
    for (int t = 0; t < 9; t++) {
        #pragma unroll
        for (int j = 0; j < 2; j++) {
            float v = wo[(j * 64 + lane) * 9 + t];
            u64 b = __ballot(v < 0.0f);
            if (lane == 0) wbits[(o * 9 + t) * 2 + j] = b;
        }
    }
    if (lane == 0) {
        float inv = gamma[o] * rsqrtf(bn_var[o] + 1e-5f);
        A[o] = scale * inv;
        B[o] = beta[o] - bn_mean[o] * inv;
    }
}

// ---------------------------------------------------------------------------
// Kernel 2: binarize x into padded bit-plane array.
//   One thread per PADDED pixel (n, ph, pw). Channel loop is coalesced across
//   lanes (consecutive threads = consecutive linear pixels in the slice).
//   Border pixels write all-zero (z=0 -> contributes 0, exact zero padding).
// ---------------------------------------------------------------------------
__global__ void pack_x_kernel(const float* __restrict__ x,
                              ulonglong4* __restrict__ xb,
                              unsigned* __restrict__ xcnt) {
    int g = blockIdx.x * 256 + threadIdx.x;     // 0..NPAD-1
    int n  = g / PHW_;
    int r  = g - n * PHW_;
    int ph = r / PW_;
    int pw = r - ph * PW_;
    int h = ph - 1, w = pw - 1;

    unsigned p0 = 0, p1 = 0, p2 = 0, p3 = 0;    // sign bits (1 = negative)
    unsigned q0 = 0, q1 = 0, q2 = 0, q3 = 0;    // nonzero bits
    unsigned cnt = 0;

    if ((unsigned)h < (unsigned)H_ && (unsigned)w < (unsigned)W_) {
        const float* xp = x + (size_t)n * C_ * HW_ + h * W_ + w;
        #pragma unroll 16
        for (int c = 0; c < 32; c++) {
            float v = xp[(size_t)c * HW_];
            unsigned neg = (v < 0.f), nz = (v != 0.f);
            p0 |= neg << c; q0 |= nz << c; cnt += nz;
        }
        #pragma unroll 16
        for (int c = 0; c < 32; c++) {
            float v = xp[(size_t)(32 + c) * HW_];
            unsigned neg = (v < 0.f), nz = (v != 0.f);
            p1 |= neg << c; q1 |= nz << c; cnt += nz;
        }
        #pragma unroll 16
        for (int c = 0; c < 32; c++) {
            float v = xp[(size_t)(64 + c) * HW_];
            unsigned neg = (v < 0.f), nz = (v != 0.f);
            p2 |= neg << c; q2 |= nz << c; cnt += nz;
        }
        #pragma unroll 16
        for (int c = 0; c < 32; c++) {
            float v = xp[(size_t)(96 + c) * HW_];
            unsigned neg = (v < 0.f), nz = (v != 0.f);
            p3 |= neg << c; q3 |= nz << c; cnt += nz;
        }
    }
    ulonglong4 o4;
    o4.x = (u64)p0 | ((u64)p1 << 32);   // s0: channels 0..63
    o4.y = (u64)p2 | ((u64)p3 << 32);   // s1: channels 64..127
    o4.z = (u64)q0 | ((u64)q1 << 32);   // z0
    o4.w = (u64)q2 | ((u64)q3 << 32);   // z1
    xb[g]   = o4;
    xcnt[g] = cnt;
}

// ---------------------------------------------------------------------------
// Kernel 3: XNOR-popcount conv + BN + residual.
//   Thread = output pixel. 9-tap x bit-words live in registers across the
//   whole o-loop; weight word-pairs are broadcast ds_read_b128 from LDS.
//   dot = sum_taps( popc(z) - 2*popc((sx^sw)&z) ) = cbase - 2*pc.
// ---------------------------------------------------------------------------
__global__ __launch_bounds__(256) void bconv_kernel(
        const ulonglong4* __restrict__ xb,
        const unsigned*   __restrict__ xcnt,
        const ulonglong2* __restrict__ wbits,   // [128][9] pairs
        const float* __restrict__ Ag, const float* __restrict__ Bg,
        const float* __restrict__ x, float* __restrict__ out) {
    __shared__ ulonglong2 w_s[1152];            // 18 KiB
    __shared__ float A_s[128], B_s[128];

    const int tid = threadIdx.x;
    for (int i = tid; i < 1152; i += 256) w_s[i] = wbits[i];
    if (tid < 128) { A_s[tid] = Ag[tid]; B_s[tid] = Bg[tid]; }
    __syncthreads();

    int g = blockIdx.x * 256 + tid;             // 0..NPIX-1
    int n = g / HW_;
    int r = g - n * HW_;
    int h = r / W_;
    int w = r - h * W_;
    int pb = (n * PH_ + h + 1) * PW_ + (w + 1); // padded center index

    u64 sx[9], sy[9], zx[9], zy[9];
    int cbase = 0;
    #pragma unroll
    for (int dh = 0; dh < 3; dh++) {
        #pragma unroll
        for (int dw = 0; dw < 3; dw++) {
            int idx = pb + (dh - 1) * PW_ + (dw - 1);
            int k = dh * 3 + dw;
            ulonglong4 t4 = xb[idx];
            sx[k] = t4.x; sy[k] = t4.y; zx[k] = t4.z; zy[k] = t4.w;
            cbase += (int)xcnt[idx];
        }
    }

    const float* xr = x   + (size_t)n * C_ * HW_ + r;
    float*       op = out + (size_t)n * C_ * HW_ + r;

    for (int o = 0; o < 128; o++) {
        int pc = 0;
        #pragma unroll
        for (int k = 0; k < 9; k++) {
            ulonglong2 ww = w_s[o * 9 + k];
            pc += __popcll((sx[k] ^ ww.x) & zx[k]);
            pc += __popcll((sy[k] ^ ww.y) & zy[k]);
        }
        float y = fmaf(A_s[o], (float)(cbase - 2 * pc), B_s[o]);
        op[(size_t)o * HW_] = y + xr[(size_t)o * HW_];
    }
}

// ---------------------------------------------------------------------------
extern "C" void kernel_launch(void* const* d_in, const int* in_sizes, int n_in,
                              void* d_out, int out_size, void* d_ws, size_t ws_size,
                              hipStream_t stream) {
    const float* x      = (const float*)d_in[0];
    const float* weight = (const float*)d_in[1];
    const float* gamma  = (const float*)d_in[2];
    const float* beta   = (const float*)d_in[3];
    const float* bnmean = (const float*)d_in[4];
    const float* bnvar  = (const float*)d_in[5];
    float* out = (float*)d_out;

    char* ws = (char*)d_ws;
    u64*        wbits = (u64*)ws;                         // 128*9*2*8 = 18432 B
    float*      A     = (float*)(ws + 18432);             // 512 B
    float*      B     = (float*)(ws + 18944);             // 512 B
    ulonglong4* xb    = (ulonglong4*)(ws + 19456);        // NPAD*32 = 6,889,472 B
    unsigned*   xcnt  = (unsigned*)(ws + 19456 + (size_t)NPAD * 32); // NPAD*4 B
    // total ws use: ~7.77 MB

    prep_w_kernel<<<128, 64, 0, stream>>>(weight, gamma, beta, bnmean, bnvar,
                                          wbits, A, B);
    pack_x_kernel<<<NPAD / 256, 256, 0, stream>>>(x, xb, xcnt);
    bconv_kernel<<<NPIX / 256, 256, 0, stream>>>(xb, xcnt,
                                                 (const ulonglong2*)wbits, A, B,
                                                 x, out);
}

// Round 2
// 280.815 us; speedup vs baseline: 1.0542x; 1.0542x over previous
//
#include <hip/hip_runtime.h>

// ReActNet BasicBlock forward:
//   out = BN(binary_conv3x3(sign(x), scale*sign(w))) + x
// XNOR-popcount conv over channel-bit-packed x. Hot path is xor+popc only;
// zero padding handled via per-border-pattern precomputed correction
// (padsum), exact x==0 values via a rare masked slow path (detected by
// nonzero-count mismatch).

#define N_   64
#define C_   128
#define H_   56
#define W_   56
#define HW_  (H_*W_)       // 3136
#define PH_  (H_+2)        // 58
#define PW_  (W_+2)        // 58
#define PHW_ (PH_*PW_)     // 3364
#define NPIX (N_*HW_)      // 200704
#define NPAD (N_*PHW_)     // 215296

typedef unsigned long long u64;

// ---------------------------------------------------------------------------
// Kernel 1: weight prep. One wave per output channel.
// ---------------------------------------------------------------------------
__global__ void prep_w_kernel(const float* __restrict__ w,
                              const float* __restrict__ gamma,
                              const float* __restrict__ beta,
                              const float* __restrict__ bn_mean,
                              const float* __restrict__ bn_var,
                              u64* __restrict__ wbits,
                              float* __restrict__ A, float* __restrict__ B) {
    const int o = blockIdx.x;
    const int lane = threadIdx.x;          // 0..63
    const float* wo = w + o * 1152;        // [i][kh][kw] flat, i*9 + tap

    float s = 0.f;
    #pragma unroll
    for (int k = 0; k < 18; k++) s += fabsf(wo[k * 64 + lane]);
    #pragma unroll
    for (int off = 32; off > 0; off >>= 1) s += __shfl_down(s, off);
    float scale = __shfl(s, 0) * (1.0f / 1152.0f);

    #pragma unroll
    for (int t = 0; t < 9; t++) {
        #pragma unroll
        for (int j = 0; j < 2; j++) {
            float v = wo[(j * 64 + lane) * 9 + t];
            u64 b = __ballot(v < 0.0f);
            if (lane == 0) wbits[(o * 9 + t) * 2 + j] = b;
        }
    }
    if (lane == 0) {
        float inv = gamma[o] * rsqrtf(bn_var[o] + 1e-5f);
        A[o] = scale * inv;
        B[o] = beta[o] - bn_mean[o] * inv;
    }
}

// ---------------------------------------------------------------------------
// Kernel 2: binarize x into padded bit planes (SoA: sign words / nonzero
// words / nonzero count). Border pixels are all-zero.
// ---------------------------------------------------------------------------
__global__ __launch_bounds__(256) void pack_x_kernel(
        const float* __restrict__ x,
        ulonglong2* __restrict__ xbs,
        ulonglong2* __restrict__ xbz,
        unsigned* __restrict__ xcnt) {
    int g = blockIdx.x * 256 + threadIdx.x;     // 0..NPAD-1
    int n  = g / PHW_;
    int r  = g - n * PHW_;
    int ph = r / PW_;
    int pw = r - ph * PW_;
    int h = ph - 1, w = pw - 1;

    unsigned p[4] = {0,0,0,0};
    unsigned z[4] = {0,0,0,0};

    if ((unsigned)h < (unsigned)H_ && (unsigned)w < (unsigned)W_) {
        const unsigned* xp =
            (const unsigned*)(x + (size_t)n * C_ * HW_ + h * W_ + w);
        #pragma unroll
        for (int j = 0; j < 4; j++) {
            unsigned pj = 0, zj = 0;
            #pragma unroll
            for (int c = 0; c < 32; c++) {
                unsigned u = xp[(size_t)(j * 32 + c) * HW_];
                pj |= (u >> 31) << c;               // sign bit
                zj |= ((u << 1) != 0u ? 1u : 0u) << c; // nonzero (ignores -0.0)
            }
            p[j] = pj; z[j] = zj;
        }
    }
    ulonglong2 s2, z2;
    s2.x = (u64)p[0] | ((u64)p[1] << 32);
    s2.y = (u64)p[2] | ((u64)p[3] << 32);
    z2.x = (u64)z[0] | ((u64)z[1] << 32);
    z2.y = (u64)z[2] | ((u64)z[3] << 32);
    xbs[g] = s2;
    xbz[g] = z2;
    xcnt[g] = __popc(z[0]) + __popc(z[1]) + __popc(z[2]) + __popc(z[3]);
}

// ---------------------------------------------------------------------------
// Kernel 3: XNOR-popcount conv + BN + residual.
//   grid = (784, 2): blockIdx.y picks a 64-wide output-channel half.
//   Fast path: pc = sum popc(sx^sw); dot = 1152 - 2*pc - padsum[pattern][o].
//   Slow path (neighborhood contains exact zero): masked with z from global.
// ---------------------------------------------------------------------------
__device__ __forceinline__ int tapmask_of(int idx) {
    int tm = 0;
    if (idx & 1) tm |= 0x007;   // top row padded:    taps 0,1,2
    if (idx & 2) tm |= 0x1C0;   // bottom row padded: taps 6,7,8
    if (idx & 4) tm |= 0x049;   // left col padded:   taps 0,3,6
    if (idx & 8) tm |= 0x124;   // right col padded:  taps 2,5,8
    return tm;
}

__global__ __launch_bounds__(256, 6) void bconv_kernel(
        const ulonglong2* __restrict__ xbs,
        const ulonglong2* __restrict__ xbz,
        const unsigned*   __restrict__ xcnt,
        const ulonglong2* __restrict__ wbits,   // [128][9] pairs
        const float* __restrict__ Ag, const float* __restrict__ Bg,
        const float* __restrict__ x, float* __restrict__ out) {
    __shared__ ulonglong2 w_s[576];             // 64 o x 9 taps, 9 KiB
    __shared__ int   psum_s[16 * 64];           // 4 KiB
    __shared__ float A_s[64], B_s[64];

    const int tid = threadIdx.x;
    const int obase = blockIdx.y * 64;

    for (int i = tid; i < 576; i += 256) w_s[i] = wbits[obase * 9 + i];
    if (tid < 64) { A_s[tid] = Ag[obase + tid]; B_s[tid] = Bg[obase + tid]; }
    __syncthreads();

    // padsum[idx][o] = sum over padded taps of (128 - 2*popc(w words))
    for (int e = tid; e < 1024; e += 256) {
        int idx = e >> 6, o = e & 63;
        int tm = tapmask_of(idx);
        int s = 0;
        #pragma unroll
        for (int t = 0; t < 9; t++) {
            if ((tm >> t) & 1) {
                ulonglong2 ww = w_s[o * 9 + t];
                s += 128 - 2 * (__popcll(ww.x) + __popcll(ww.y));
            }
        }
        psum_s[e] = s;
    }
    __syncthreads();

    int g = blockIdx.x * 256 + tid;             // 0..NPIX-1
    int n = g / HW_;
    int r = g - n * HW_;
    int h = r / W_;
    int w = r - h * W_;
    int pb = (n * PH_ + h + 1) * PW_ + (w + 1); // padded center index

    u64 sx[9], sy[9];
    int taps_off[9];
    int csum = 0;
    #pragma unroll
    for (int dh = 0; dh < 3; dh++) {
        #pragma unroll
        for (int dw = 0; dw < 3; dw++) {
            int k = dh * 3 + dw;
            int idx = pb + (dh - 1) * PW_ + (dw - 1);
            taps_off[k] = idx;
            ulonglong2 t2 = xbs[idx];
            sx[k] = t2.x; sy[k] = t2.y;
            csum += (int)xcnt[idx];
        }
    }

    int pidx = (h == 0 ? 1 : 0) | (h == H_-1 ? 2 : 0) |
               (w == 0 ? 4 : 0) | (w == W_-1 ? 8 : 0);
    int valid = 9 - __popc(tapmask_of(pidx));
    bool slow = (csum != 128 * valid);

    const float* xr = x   + ((size_t)n * C_ + obase) * HW_ + r;
    float*       op = out + ((size_t)n * C_ + obase) * HW_ + r;
    const int* psp = &psum_s[pidx * 64];

    if (!slow) {
        #pragma unroll 2
        for (int o = 0; o < 64; o++) {
            int pc = 0;
            #pragma unroll
            for (int k = 0; k < 9; k++) {
                ulonglong2 ww = w_s[o * 9 + k];
                pc += __popcll(sx[k] ^ ww.x);
                pc += __popcll(sy[k] ^ ww.y);
            }
            int dot = 1152 - 2 * pc - psp[o];
            op[o * HW_] = fmaf(A_s[o], (float)dot, B_s[o]) + xr[o * HW_];
        }
    } else {
        // rare: some x==0 (or -0.0) in the 9-tap neighborhood
        for (int o = 0; o < 64; o++) {
            int pc = 0;
            #pragma unroll
            for (int k = 0; k < 9; k++) {
                ulonglong2 ww = w_s[o * 9 + k];
                ulonglong2 zz = xbz[taps_off[k]];
                pc += __popcll((sx[k] ^ ww.x) & zz.x);
                pc += __popcll((sy[k] ^ ww.y) & zz.y);
            }
            int dot = csum - 2 * pc;
            op[o * HW_] = fmaf(A_s[o], (float)dot, B_s[o]) + xr[o * HW_];
        }
    }
}

// ---------------------------------------------------------------------------
extern "C" void kernel_launch(void* const* d_in, const int* in_sizes, int n_in,
                              void* d_out, int out_size, void* d_ws, size_t ws_size,
                              hipStream_t stream) {
    const float* x      = (const float*)d_in[0];
    const float* weight = (const float*)d_in[1];
    const float* gamma  = (const float*)d_in[2];
    const float* beta   = (const float*)d_in[3];
    const float* bnmean = (const float*)d_in[4];
    const float* bnvar  = (const float*)d_in[5];
    float* out = (float*)d_out;

    char* ws = (char*)d_ws;
    u64*        wbits = (u64*)ws;                         // 18432 B
    float*      A     = (float*)(ws + 18432);             // 512 B
    float*      B     = (float*)(ws + 18944);             // 512 B
    ulonglong2* xbs   = (ulonglong2*)(ws + 19456);                        // NPAD*16
    ulonglong2* xbz   = (ulonglong2*)(ws + 19456 + (size_t)NPAD * 16);    // NPAD*16
    unsigned*   xcnt  = (unsigned*)(ws + 19456 + (size_t)NPAD * 32);      // NPAD*4
    // total ws use: ~7.77 MB

    prep_w_kernel<<<128, 64, 0, stream>>>(weight, gamma, beta, bnmean, bnvar,
                                          wbits, A, B);
    pack_x_kernel<<<NPAD / 256, 256, 0, stream>>>(x, xbs, xbz, xcnt);
    dim3 cgrid(NPIX / 256, 2);
    bconv_kernel<<<cgrid, 256, 0, stream>>>(xbs, xbz, xcnt,
                                            (const ulonglong2*)wbits, A, B,
                                            x, out);
}

// Round 3
// 272.083 us; speedup vs baseline: 1.0881x; 1.0321x over previous
//
#include <hip/hip_runtime.h>

// ReActNet BasicBlock forward:
//   out = BN(binary_conv3x3(sign(x), scale*sign(w))) + x
// XNOR-popcount conv. Weights are wave-uniform -> fetched via scalar loads
// (SGPRs), not LDS. Zero padding folded into per-(border-pattern, o) bias;
// exact x==0 handled by rare masked slow path.

#define N_   64
#define C_   128
#define H_   56
#define W_   56
#define HW_  (H_*W_)       // 3136
#define PH_  (H_+2)        // 58
#define PW_  (W_+2)        // 58
#define PHW_ (PH_*PW_)     // 3364
#define NPIX (N_*HW_)      // 200704
#define NPAD (N_*PHW_)     // 215296

typedef unsigned long long u64;

// ---------------------------------------------------------------------------
// Kernel 1: weight prep. One wave per output channel.
//   wbits flat layout: [o][tap][j]  (18 u64 = 144 B per o, contiguous)
// ---------------------------------------------------------------------------
__global__ void prep_w_kernel(const float* __restrict__ w,
                              const float* __restrict__ gamma,
                              const float* __restrict__ beta,
                              const float* __restrict__ bn_mean,
                              const float* __restrict__ bn_var,
                              u64* __restrict__ wbits,
                              float* __restrict__ A, float* __restrict__ B) {
    const int o = blockIdx.x;
    const int lane = threadIdx.x;          // 0..63
    const float* wo = w + o * 1152;        // [i][kh][kw] flat, i*9 + tap

    float s = 0.f;
    #pragma unroll
    for (int k = 0; k < 18; k++) s += fabsf(wo[k * 64 + lane]);
    #pragma unroll
    for (int off = 32; off > 0; off >>= 1) s += __shfl_down(s, off);
    float scale = __shfl(s, 0) * (1.0f / 1152.0f);

    #pragma unroll
    for (int t = 0; t < 9; t++) {
        #pragma unroll
        for (int j = 0; j < 2; j++) {
            float v = wo[(j * 64 + lane) * 9 + t];
            u64 b = __ballot(v < 0.0f);
            if (lane == 0) wbits[(o * 9 + t) * 2 + j] = b;
        }
    }
    if (lane == 0) {
        float inv = gamma[o] * rsqrtf(bn_var[o] + 1e-5f);
        A[o] = scale * inv;
        B[o] = beta[o] - bn_mean[o] * inv;
    }
}

// ---------------------------------------------------------------------------
// Kernel 2: binarize x, 2 pixels per thread (float2 loads).
//   Writes padded-layout sign words / nonzero words / nonzero counts for the
//   INTERIOR pixels only; border handled by border_kernel.
// ---------------------------------------------------------------------------
__global__ __launch_bounds__(256) void pack_x_kernel(
        const float* __restrict__ x,
        ulonglong2* __restrict__ xbs,
        ulonglong2* __restrict__ xbz,
        unsigned* __restrict__ xcnt) {
    int t = blockIdx.x * 256 + threadIdx.x;     // 0..NPIX/2-1
    int p = t * 2;
    int n = p / HW_;
    int r = p - n * HW_;
    int h = r / W_;
    int w = r - h * W_;                          // even (W_ even, p even)

    const float2* xp = (const float2*)(x + (size_t)n * C_ * HW_ + h * W_ + w);

    unsigned pa[4], za[4], pb[4], zb[4];
    #pragma unroll
    for (int j = 0; j < 4; j++) { pa[j]=0; za[j]=0; pb[j]=0; zb[j]=0; }

    #pragma unroll
    for (int j = 0; j < 4; j++) {
        unsigned paj = 0, zaj = 0, pbj = 0, zbj = 0;
        #pragma unroll 16
        for (int c = 0; c < 32; c++) {
            float2 v = xp[(size_t)(j * 32 + c) * (HW_ / 2)];
            unsigned ua = __float_as_uint(v.x);
            unsigned ub = __float_as_uint(v.y);
            paj |= (ua >> 31) << c;
            zaj |= ((ua << 1) != 0u ? 1u : 0u) << c;
            pbj |= (ub >> 31) << c;
            zbj |= ((ub << 1) != 0u ? 1u : 0u) << c;
        }
        pa[j]=paj; za[j]=zaj; pb[j]=pbj; zb[j]=zbj;
    }

    int pg = (n * PH_ + h + 1) * PW_ + (w + 1);
    ulonglong2 s2, z2;
    s2.x = (u64)pa[0] | ((u64)pa[1] << 32);
    s2.y = (u64)pa[2] | ((u64)pa[3] << 32);
    z2.x = (u64)za[0] | ((u64)za[1] << 32);
    z2.y = (u64)za[2] | ((u64)za[3] << 32);
    xbs[pg] = s2; xbz[pg] = z2;
    xcnt[pg] = __popc(za[0]) + __popc(za[1]) + __popc(za[2]) + __popc(za[3]);

    s2.x = (u64)pb[0] | ((u64)pb[1] << 32);
    s2.y = (u64)pb[2] | ((u64)pb[3] << 32);
    z2.x = (u64)zb[0] | ((u64)zb[1] << 32);
    z2.y = (u64)zb[2] | ((u64)zb[3] << 32);
    xbs[pg + 1] = s2; xbz[pg + 1] = z2;
    xcnt[pg + 1] = __popc(zb[0]) + __popc(zb[1]) + __popc(zb[2]) + __popc(zb[3]);
}

// ---------------------------------------------------------------------------
// Kernel 2b: zero the padded border entries.
// ---------------------------------------------------------------------------
__global__ void border_kernel(ulonglong2* __restrict__ xbs,
                              ulonglong2* __restrict__ xbz,
                              unsigned* __restrict__ xcnt) {
    int bt = blockIdx.x * 256 + threadIdx.x;
    if (bt >= N_ * 228) return;                 // 2*58 + 2*56 = 228 per image
    int n = bt / 228, e = bt - n * 228;
    int ph, pw;
    if (e < 58)       { ph = 0;  pw = e; }
    else if (e < 116) { ph = 57; pw = e - 58; }
    else { int i = e - 116; ph = 1 + (i >> 1); pw = (i & 1) ? 57 : 0; }
    int g = (n * PH_ + ph) * PW_ + pw;
    ulonglong2 zz; zz.x = 0; zz.y = 0;
    xbs[g] = zz; xbz[g] = zz; xcnt[g] = 0;
}

// ---------------------------------------------------------------------------
// Kernel 3: XNOR-popcount conv + BN + residual.
//   grid = (784, 2): blockIdx.y picks a 64-wide output-channel half.
//   Weights read via scalar loads (uniform address). Per-pattern bias
//   B'[pidx][o] = B[o] - A[o]*padsum[pidx][o] precomputed in LDS as float2
//   {A, B'} -> one ds_read_b64 per o in the epilogue.
// ---------------------------------------------------------------------------
__device__ __forceinline__ int tapmask_of(int idx) {
    int tm = 0;
    if (idx & 1) tm |= 0x007;   // top row padded
    if (idx & 2) tm |= 0x1C0;   // bottom row padded
    if (idx & 4) tm |= 0x049;   // left col padded
    if (idx & 8) tm |= 0x124;   // right col padded
    return tm;
}

__global__ __launch_bounds__(256, 6) void bconv_kernel(
        const ulonglong2* __restrict__ xbs,
        const ulonglong2* __restrict__ xbz,
        const unsigned*   __restrict__ xcnt,
        const u64* __restrict__ wbits,          // [128][18] u64
        const float* __restrict__ Ag, const float* __restrict__ Bg,
        const float* __restrict__ x, float* __restrict__ out) {
    __shared__ float2 AB_s[16 * 64];            // {A[o], B'[pidx][o]}, 8 KiB

    const int tid = threadIdx.x;
    const int obase = blockIdx.y * 64;

    // Precompute per-pattern folded bias.
    for (int e = tid; e < 1024; e += 256) {
        int idx = e >> 6, o = (e & 63);
        int tm = tapmask_of(idx);
        const u64* wp = wbits + (size_t)(obase + o) * 18;
        int s = 0;
        #pragma unroll
        for (int t = 0; t < 9; t++) {
            if ((tm >> t) & 1)
                s += 128 - 2 * (__popcll(wp[2*t]) + __popcll(wp[2*t+1]));
        }
        float a = Ag[obase + o];
        float2 ab; ab.x = a; ab.y = Bg[obase + o] - a * (float)s;
        AB_s[e] = ab;
    }
    __syncthreads();

    int g = blockIdx.x * 256 + tid;             // 0..NPIX-1
    int n = g / HW_;
    int r = g - n * HW_;
    int h = r / W_;
    int w = r - h * W_;
    int pb = (n * PH_ + h + 1) * PW_ + (w + 1);

    u64 sx[9], sy[9];
    int taps_off[9];
    int csum = 0;
    #pragma unroll
    for (int dh = 0; dh < 3; dh++) {
        #pragma unroll
        for (int dw = 0; dw < 3; dw++) {
            int k = dh * 3 + dw;
            int idx = pb + (dh - 1) * PW_ + (dw - 1);
            taps_off[k] = idx;
            ulonglong2 t2 = xbs[idx];
            sx[k] = t2.x; sy[k] = t2.y;
            csum += (int)xcnt[idx];
        }
    }

    int pidx = (h == 0 ? 1 : 0) | (h == H_-1 ? 2 : 0) |
               (w == 0 ? 4 : 0) | (w == W_-1 ? 8 : 0);
    int valid = 9 - __popc(tapmask_of(pidx));
    bool slow = (csum != 128 * valid);

    const float* xr = x   + ((size_t)n * C_ + obase) * HW_ + r;
    float*       op = out + ((size_t)n * C_ + obase) * HW_ + r;
    const float2* abp = &AB_s[pidx << 6];

    if (!slow) {
        const u64* wp = wbits + (size_t)obase * 18;
        #pragma unroll 2
        for (int o = 0; o < 64; o++) {
            int pc = 0;
            #pragma unroll
            for (int k = 0; k < 9; k++) {
                pc += __popcll(sx[k] ^ wp[2*k]);
                pc += __popcll(sy[k] ^ wp[2*k+1]);
            }
            wp += 18;
            float2 ab = abp[o];
            float dot = (float)(1152 - 2 * pc);
            op[o * HW_] = fmaf(ab.x, dot, ab.y) + xr[o * HW_];
        }
    } else {
        // rare: some x==0 (or -0.0) in the 9-tap neighborhood
        for (int o = 0; o < 64; o++) {
            const u64* wp = wbits + (size_t)(obase + o) * 18;
            int pc = 0;
            #pragma unroll
            for (int k = 0; k < 9; k++) {
                ulonglong2 zz = xbz[taps_off[k]];
                pc += __popcll((sx[k] ^ wp[2*k])   & zz.x);
                pc += __popcll((sy[k] ^ wp[2*k+1]) & zz.y);
            }
            float a = abp[o].x;
            int dot = csum - 2 * pc;
            op[o * HW_] = fmaf(a, (float)dot, Bg[obase + o]) + xr[o * HW_];
        }
    }
}

// ---------------------------------------------------------------------------
extern "C" void kernel_launch(void* const* d_in, const int* in_sizes, int n_in,
                              void* d_out, int out_size, void* d_ws, size_t ws_size,
                              hipStream_t stream) {
    const float* x      = (const float*)d_in[0];
    const float* weight = (const float*)d_in[1];
    const float* gamma  = (const float*)d_in[2];
    const float* beta   = (const float*)d_in[3];
    const float* bnmean = (const float*)d_in[4];
    const float* bnvar  = (const float*)d_in[5];
    float* out = (float*)d_out;

    char* ws = (char*)d_ws;
    u64*        wbits = (u64*)ws;                         // 18432 B
    float*      A     = (float*)(ws + 18432);             // 512 B
    float*      B     = (float*)(ws + 18944);             // 512 B
    ulonglong2* xbs   = (ulonglong2*)(ws + 19456);                        // NPAD*16
    ulonglong2* xbz   = (ulonglong2*)(ws + 19456 + (size_t)NPAD * 16);    // NPAD*16
    unsigned*   xcnt  = (unsigned*)(ws + 19456 + (size_t)NPAD * 32);      // NPAD*4

    prep_w_kernel<<<128, 64, 0, stream>>>(weight, gamma, beta, bnmean, bnvar,
                                          wbits, A, B);
    pack_x_kernel<<<NPIX / 2 / 256, 256, 0, stream>>>(x, xbs, xbz, xcnt);
    border_kernel<<<(N_ * 228 + 255) / 256, 256, 0, stream>>>(xbs, xbz, xcnt);
    dim3 cgrid(NPIX / 256, 2);
    bconv_kernel<<<cgrid, 256, 0, stream>>>(xbs, xbz, xcnt, wbits, A, B,
                                            x, out);
}